// Round 9
// baseline (608.351 us; speedup 1.0000x reference)
//
#include <hip/hip_runtime.h>
#include <stdint.h>
#include <stdio.h>

#define BB   16
#define LL   512
#define CC   384
#define FF   384
#define KW   3
#define MEL  4096
#define KKT  (CC*KW)   // 1152

// output section offsets (fp32 elements)
#define O_OUT 0
#define N_OUT (BB*MEL*CC)          // 25165824
#define O_DUR (N_OUT)
#define O_PIT (O_DUR + BB*LL)
#define O_EN  (O_PIT + BB*MEL)

using bf16x8 = __attribute__((ext_vector_type(8))) short;
using f32x4  = __attribute__((ext_vector_type(4))) float;

__device__ __forceinline__ unsigned short f2bf(float v) {
    union { float f; unsigned int u; } cv; cv.f = v;
    unsigned int u = cv.u;
    u += 0x7FFFu + ((u >> 16) & 1u);   // RNE
    return (unsigned short)(u >> 16);
}
__device__ __forceinline__ float bf2f(unsigned short u) {
    union { unsigned int u; float f; } cv; cv.u = ((unsigned int)u) << 16; return cv.f;
}

__device__ __forceinline__ void gld_lds16(const unsigned short* gp, unsigned short* lp) {
    __builtin_amdgcn_global_load_lds(
        (const __attribute__((address_space(1))) unsigned int*)gp,
        (__attribute__((address_space(3))) unsigned int*)lp, 16, 0, 0);
}

// ------ weight transform: w[F][C][K] fp32 -> wt2 step-major chunk-major ----
// wt2[t][c][e]: t in 0..17 (K-step of 64), c = q*384+bn (q=chunk 0..7, bn=col),
// e = 0..7 shorts. Element = w[bn][ch][k] with kk = t*64+q*8+e, ch=kk%384, k=kk/384.
__global__ void wtrans_kernel(const float* __restrict__ w, unsigned short* __restrict__ wt2) {
    int i = blockIdx.x * 256 + threadIdx.x;
    if (i >= FF * KKT) return;
    const int t = i / 24576;
    const int r = i - t * 24576;
    const int c = r >> 3;
    const int e = r & 7;
    const int q = c / 384;
    const int bn = c - q * 384;
    const int kk = t * 64 + q * 8 + e;
    const int k = kk / CC;
    const int ch = kk - k * CC;
    wt2[i] = f2bf(w[(size_t)bn * KKT + ch * KW + k]);
}

// ---------------- x fp32 -> padded bf16 [B][L+2][C] ------------------------
__global__ void convert_x_kernel(const float* __restrict__ x, unsigned short* __restrict__ o) {
    int i = blockIdx.x * 256 + threadIdx.x;
    if (i >= BB * LL * CC) return;
    int b = i / (LL * CC);
    int r = i - b * (LL * CC);
    int t = r / CC;
    int c = r - t * CC;
    o[((size_t)b * (LL + 2) + t + 1) * CC + c] = f2bf(x[i]);
}

// ---------------- zero the two pad rows per batch --------------------------
__global__ void zpad_kernel(unsigned short* __restrict__ buf, int T) {
    int b = blockIdx.x >> 1;
    int w = blockIdx.x & 1;
    size_t row = (size_t)b * (T + 2) + (w ? (T + 1) : 0);
    buf[row * CC + threadIdx.x] = 0;
}

// ---------------- fused Conv(K=3)+bias+ReLU+LN [+Linear] -------------------
// Tile M=256 x N=384, BK=64, NT=18 steps. 512 thr, 8 waves, layout 1M x 8N:
// each wave owns ALL 256 rows x a DISTINCT 48-col slice (zero B duplication).
// A: LDS 4x32KB circular (global_load_lds, XOR ca=q^(row&7), coalesced src).
// B: registers direct from L2-resident wt2 (256B/group contiguous).
// One barrier per K-step; every in-loop wait counted (vmcnt 7), B prefetched
// across the barrier. MFMA/step/SIMD ~3720 cyc >> fixed overhead.
template<int T, bool FL>
__global__ __launch_bounds__(512, 2)
void conv_ln_kernel(const unsigned short* __restrict__ inb,
                    const unsigned short* __restrict__ wt2,
                    const float* __restrict__ bias,
                    const float* __restrict__ g,
                    const float* __restrict__ be,
                    unsigned short* __restrict__ outb,
                    const float* __restrict__ wl,
                    const float* __restrict__ bl,
                    float* __restrict__ op) {
    __shared__ __align__(16) unsigned short LDS[4][16384];   // 4 x 32KB A buffers

    constexpr int NT = KKT / 64;   // 18
    const int m0 = blockIdx.x * 256;
    const int b  = m0 / T;
    const int t0 = m0 - b * T;
    const int tid  = threadIdx.x;
    const int lane = tid & 63;
    const int wv   = tid >> 6;         // 0..7 -> 48-col slice
    const int q0   = lane >> 4;
    const int l15  = lane & 15;

    // A staging sources (pre-swizzled within 128B row segments -> coalesced)
    const int rowS = tid >> 3;         // 0..63
    const int gch  = (tid & 7) ^ (rowS & 7);
    const unsigned short* srcA[4];
    #pragma unroll
    for (int s = 0; s < 4; ++s)
        srcA[s] = inb + ((size_t)b * (T + 2) + t0 + s * 64 + rowS) * CC + gch * 8;
    // B fragment bases: frag (q,j) at wt2 + t*24576 + (q*384 + wv*48 + j*16 + l15)*8
    const unsigned short* wtb0 = wt2 + (size_t)((q0)     * 384 + wv * 48 + l15) * 8;
    const unsigned short* wtb1 = wt2 + (size_t)((4 + q0) * 384 + wv * 48 + l15) * 8;

    f32x4 acc[16][3] = {};
    bf16x8 bA[3], bB[3];

    auto stageA = [&](int bi, int t) {      // 4 VMEM ops
        const int off = t * 64;             // padded layout folds the tap shift
        #pragma unroll
        for (int s = 0; s < 4; ++s)
            gld_lds16(srcA[s] + off, &LDS[bi][s * 4096 + wv * 512]);
    };
    auto loadB0 = [&](int t) {              // 3 VMEM ops
        const unsigned short* p = wtb0 + (size_t)t * 24576;
        #pragma unroll
        for (int j = 0; j < 3; ++j) bA[j] = *(const bf16x8*)(p + j * 128);
    };
    auto loadB1 = [&](int t) {              // 3 VMEM ops
        const unsigned short* p = wtb1 + (size_t)t * 24576;
        #pragma unroll
        for (int j = 0; j < 3; ++j) bB[j] = *(const bf16x8*)(p + j * 128);
    };
    auto computeK = [&](int bi, int kkq, const bf16x8* br) {
        const int ca = kkq ^ (lane & 7);
        __builtin_amdgcn_s_setprio(1);
        #pragma unroll
        for (int gp = 0; gp < 4; ++gp) {    // af in groups of 4 (cap liveness)
            bf16x8 af[4];
            #pragma unroll
            for (int ii = 0; ii < 4; ++ii) {
                const int ar = (gp * 4 + ii) * 16 + l15;
                af[ii] = *(const bf16x8*)(&LDS[bi][ar * 64 + ca * 8]);
            }
            #pragma unroll
            for (int ii = 0; ii < 4; ++ii)
                #pragma unroll
                for (int j = 0; j < 3; ++j)
                    acc[gp * 4 + ii][j] = __builtin_amdgcn_mfma_f32_16x16x32_bf16(
                        af[ii], br[j], acc[gp * 4 + ii][j], 0, 0, 0);
        }
        __builtin_amdgcn_s_setprio(0);
    };

    // prologue
    stageA(0, 0);                                      // out 4
    stageA(1, 1);                                      // out 8
    loadB0(0);                                         // out 11
    asm volatile("s_waitcnt vmcnt(3)" ::: "memory");   // stages 0,1 landed

    #pragma unroll 1
    for (int t = 0; t < NT; ++t) {
        __builtin_amdgcn_s_barrier();          // A(t) ready for all waves
        asm volatile("" ::: "memory");
        loadB1(t);                                             // +3
        stageA((t + 2) & 3, (t + 2 > NT - 1) ? NT - 1 : t + 2); // +4
        asm volatile("s_waitcnt vmcnt(7)" ::: "memory");  // bA(t) landed
        computeK(t & 3, q0, bA);               // 48 MFMA
        loadB0((t + 1 > NT - 1) ? NT - 1 : t + 1);             // +3
        asm volatile("s_waitcnt vmcnt(7)" ::: "memory");  // bB(t) landed
        computeK(t & 3, 4 + q0, bB);           // 48 MFMA
        // at this point: outstanding = stage(t+2)[4] + bA(t+1)[3] = 7;
        // everything older (incl stage(t+1)) has landed -> next barrier safe
    }
    asm volatile("s_waitcnt vmcnt(0)" ::: "memory");
    __syncthreads();

    // ---------------- epilogue: bias + ReLU + LN [+ Linear] ----------------
    // lane holds rows i*16 + q0*4 + r (i=0..15, r=0..3), cols wv*48 + j*16 + l15
    const int colb = wv * 48 + l15;
    float b3[3];
    #pragma unroll
    for (int j = 0; j < 3; ++j) b3[j] = bias[colb + j * 16];
    #pragma unroll
    for (int i = 0; i < 16; ++i)
        #pragma unroll
        for (int j = 0; j < 3; ++j)
            #pragma unroll
            for (int r = 0; r < 4; ++r) {
                float v = acc[i][j][r] + b3[j];
                acc[i][j][r] = v > 0.f ? v : 0.f;
            }

    // per-row partial sums within wave (reduce over 16 lanes x 3 cols)
    float2* red = (float2*)&LDS[0][0];     // [256 rows][stride 9] (pad: no conflicts)
    #pragma unroll
    for (int i = 0; i < 16; ++i)
        #pragma unroll
        for (int r = 0; r < 4; ++r) {
            float s = 0.f, s2 = 0.f;
            #pragma unroll
            for (int j = 0; j < 3; ++j) { const float v = acc[i][j][r]; s += v; s2 += v * v; }
            #pragma unroll
            for (int m = 1; m <= 8; m <<= 1) { s += __shfl_xor(s, m); s2 += __shfl_xor(s2, m); }
            if (l15 == 0)
                red[(i * 16 + q0 * 4 + r) * 9 + wv] = make_float2(s, s2);
        }
    __syncthreads();

    float g3[3], be3[3];
    #pragma unroll
    for (int j = 0; j < 3; ++j) { g3[j] = g[colb + j * 16]; be3[j] = be[colb + j * 16]; }

    if (!FL) {
        #pragma unroll
        for (int i = 0; i < 16; ++i)
            #pragma unroll
            for (int r = 0; r < 4; ++r) {
                const int row = i * 16 + q0 * 4 + r;
                float S = 0.f, Q = 0.f;
                #pragma unroll
                for (int w = 0; w < 8; ++w) {
                    const float2 p = red[row * 9 + w];
                    S += p.x; Q += p.y;
                }
                const float mu = S * (1.f / 384.f);
                const float rs = rsqrtf(Q * (1.f / 384.f) - mu * mu + 1e-5f);
                unsigned short* qp = outb + ((size_t)b * (T + 2) + t0 + row + 1) * CC + colb;
                #pragma unroll
                for (int j = 0; j < 3; ++j)
                    qp[j * 16] = f2bf((acc[i][j][r] - mu) * rs * g3[j] + be3[j]);
            }
    } else {
        float wl3[3];
        #pragma unroll
        for (int j = 0; j < 3; ++j) wl3[j] = wl[colb + j * 16];
        float* redl = (float*)&LDS[2][0];   // [256 rows][stride 9]
        #pragma unroll
        for (int i = 0; i < 16; ++i)
            #pragma unroll
            for (int r = 0; r < 4; ++r) {
                const int row = i * 16 + q0 * 4 + r;
                float S = 0.f, Q = 0.f;
                #pragma unroll
                for (int w = 0; w < 8; ++w) {
                    const float2 p = red[row * 9 + w];
                    S += p.x; Q += p.y;
                }
                const float mu = S * (1.f / 384.f);
                const float rs = rsqrtf(Q * (1.f / 384.f) - mu * mu + 1e-5f);
                float sl = 0.f;
                #pragma unroll
                for (int j = 0; j < 3; ++j)
                    sl += ((acc[i][j][r] - mu) * rs * g3[j] + be3[j]) * wl3[j];
                #pragma unroll
                for (int m = 1; m <= 8; m <<= 1) sl += __shfl_xor(sl, m);
                if (l15 == 0) redl[row * 9 + wv] = sl;
            }
        __syncthreads();
        if (tid < 256) {
            float s = bl[0];
            #pragma unroll
            for (int w = 0; w < 8; ++w) s += redl[tid * 9 + w];
            op[m0 + tid] = s;
        }
    }
}

// ---------------- cumsum of dur per batch ----------------------------------
__global__ void cumsum_kernel(const int* __restrict__ dur, int* __restrict__ cum) {
    __shared__ int s[LL];
    const int b = blockIdx.x, t = threadIdx.x;
    s[t] = dur[b * LL + t];
    __syncthreads();
    for (int off = 1; off < LL; off <<= 1) {
        int v = (t >= off) ? s[t - off] : 0;
        __syncthreads();
        s[t] += v;
        __syncthreads();
    }
    cum[b * LL + t] = s[t];
}

// ---------------- frame -> phoneme index (binary search), -1 if masked -----
__global__ void idx_kernel(const int* __restrict__ cum, int* __restrict__ idxm) {
    const int i = blockIdx.x * 256 + threadIdx.x;
    if (i >= BB * MEL) return;
    const int b = i / MEL, t = i - b * MEL;
    const int* cb = cum + b * LL;
    const int total = cb[LL - 1];
    int lo = 0, hi = LL;
    while (lo < hi) {
        const int mid = (lo + hi) >> 1;
        if (cb[mid] <= t) lo = mid + 1; else hi = mid;
    }
    int id = lo > LL - 1 ? LL - 1 : lo;
    idxm[i] = (t < total) ? id : -1;
}

// ---------------- gather: x fp32 -> expanded bf16 padded (bb0) -------------
__global__ void gather_kernel(const float* __restrict__ x, const int* __restrict__ idxm,
                              unsigned short* __restrict__ bb0) {
    const int i = blockIdx.x * 256 + threadIdx.x;   // i < BB*MEL*96
    const int row = i / 96;
    const int c4  = (i - row * 96) * 4;
    const int b = row >> 12, t = row & (MEL - 1);
    const int id = idxm[row];
    float4 v = make_float4(0.f, 0.f, 0.f, 0.f);
    if (id >= 0) v = *(const float4*)(x + ((size_t)b * LL + id) * CC + c4);
    uint2 pk;
    pk.x = (unsigned int)f2bf(v.x) | ((unsigned int)f2bf(v.y) << 16);
    pk.y = (unsigned int)f2bf(v.z) | ((unsigned int)f2bf(v.w) << 16);
    *(uint2*)(bb0 + ((size_t)b * (MEL + 2) + t + 1) * CC + c4) = pk;
}

// ---------------- be0 = bf16(bb0 + pv[row]) (energy conv input) ------------
__global__ void addp_kernel(const unsigned short* __restrict__ bb0,
                            const float* __restrict__ pv,
                            unsigned short* __restrict__ be0) {
    const int i = blockIdx.x * 256 + threadIdx.x;   // i < BB*MEL*48
    const int row = i / 48;
    const int c8  = (i - row * 48) * 8;
    const int b = row >> 12, t = row & (MEL - 1);
    const float p = pv[row];
    const size_t o = ((size_t)b * (MEL + 2) + t + 1) * CC + c8;
    const uint4 in = *(const uint4*)(bb0 + o);
    uint4 ot;
    const unsigned int w[4] = {in.x, in.y, in.z, in.w};
    unsigned int r[4];
    #pragma unroll
    for (int k = 0; k < 4; ++k) {
        const float lo = bf2f((unsigned short)w[k]) + p;
        const float hi = bf2f((unsigned short)(w[k] >> 16)) + p;
        r[k] = (unsigned int)f2bf(lo) | ((unsigned int)f2bf(hi) << 16);
    }
    ot.x = r[0]; ot.y = r[1]; ot.z = r[2]; ot.w = r[3];
    *(uint4*)(be0 + o) = ot;
}

// ---------------- out0 = x[idx] (fp32 exact) + pv + ev ---------------------
__global__ void final_kernel(const float* __restrict__ x, const int* __restrict__ idxm,
                             const float* __restrict__ pv, const float* __restrict__ ev,
                             float* __restrict__ out0) {
    const int i = blockIdx.x * 256 + threadIdx.x;   // i < BB*MEL*96
    const int row = i / 96;
    const int c4  = (i - row * 96) * 4;
    const int b = row >> 12;
    const int id = idxm[row];
    const float add = pv[row] + ev[row];
    float4 v = make_float4(0.f, 0.f, 0.f, 0.f);
    if (id >= 0) v = *(const float4*)(x + ((size_t)b * LL + id) * CC + c4);
    v.x += add; v.y += add; v.z += add; v.w += add;
    *(float4*)(out0 + (size_t)row * CC + c4) = v;
}

extern "C" void kernel_launch(void* const* d_in, const int* in_sizes, int n_in,
                              void* d_out, int out_size, void* d_ws, size_t ws_size,
                              hipStream_t stream) {
    const float* x = (const float*)d_in[0];
    const float* P[30];
    for (int i = 0; i < 30; ++i) P[i] = (const float*)d_in[1 + i];
    const int* dur = (const int*)d_in[31];
    float* out = (float*)d_out;

    char* ws = (char*)d_ws;
    const size_t WTT_ELEMS = (size_t)FF * KKT;            // 442368
    const size_t WTT_BYTES = WTT_ELEMS * 2;               // 884736
    unsigned short* wtt[6];
    for (int i = 0; i < 6; ++i) wtt[i] = (unsigned short*)(ws + i * WTT_BYTES);
    int* cum  = (int*)(ws + 5308416);
    int* idxm = (int*)(ws + 5341184);
    unsigned short* sb0 = (unsigned short*)(ws + 5603328);                 // [16][514][384]
    unsigned short* h1s = (unsigned short*)(ws + 11919360);                // [16][514][384]
    unsigned short* bb0 = (unsigned short*)(ws + 18235392);                // [16][4098][384]
    unsigned short* h1p = (unsigned short*)(ws + 68616192);                // [16][4098][384]
    unsigned short* be0 = (unsigned short*)(ws + 118996992);               // [16][4098][384]
    const size_t need = 169377792;
    if (ws_size < need)
        fprintf(stderr, "kernel_launch: ws too small: %zu < %zu\n", ws_size, need);

    const float *dp_w1=P[0], *dp_b1=P[1], *dp_g1=P[2], *dp_be1=P[3], *dp_w2=P[4],
                *dp_b2=P[5], *dp_g2=P[6], *dp_be2=P[7], *dp_wl=P[8], *dp_bl=P[9];
    const float *pp_w1=P[10], *pp_b1=P[11], *pp_g1=P[12], *pp_be1=P[13], *pp_w2=P[14],
                *pp_b2=P[15], *pp_g2=P[16], *pp_be2=P[17], *pp_wl=P[18], *pp_bl=P[19];
    const float *ep_w1=P[20], *ep_b1=P[21], *ep_g1=P[22], *ep_be1=P[23], *ep_w2=P[24],
                *ep_b2=P[25], *ep_g2=P[26], *ep_be2=P[27], *ep_wl=P[28], *ep_bl=P[29];

    const int wtg = (int)((WTT_ELEMS + 255) / 256);
    wtrans_kernel<<<wtg, 256, 0, stream>>>(dp_w1, wtt[0]);
    wtrans_kernel<<<wtg, 256, 0, stream>>>(dp_w2, wtt[1]);
    wtrans_kernel<<<wtg, 256, 0, stream>>>(pp_w1, wtt[2]);
    wtrans_kernel<<<wtg, 256, 0, stream>>>(pp_w2, wtt[3]);
    wtrans_kernel<<<wtg, 256, 0, stream>>>(ep_w1, wtt[4]);
    wtrans_kernel<<<wtg, 256, 0, stream>>>(ep_w2, wtt[5]);

    convert_x_kernel<<<(BB * LL * CC + 255) / 256, 256, 0, stream>>>(x, sb0);
    zpad_kernel<<<BB * 2, CC, 0, stream>>>(sb0, LL);
    zpad_kernel<<<BB * 2, CC, 0, stream>>>(h1s, LL);
    zpad_kernel<<<BB * 2, CC, 0, stream>>>(bb0, MEL);
    zpad_kernel<<<BB * 2, CC, 0, stream>>>(h1p, MEL);
    zpad_kernel<<<BB * 2, CC, 0, stream>>>(be0, MEL);

    cumsum_kernel<<<BB, LL, 0, stream>>>(dur, cum);
    idx_kernel<<<(BB * MEL + 255) / 256, 256, 0, stream>>>(cum, idxm);

    // duration predictor (T=512)
    conv_ln_kernel<LL, false><<<BB * LL / 256, 512, 0, stream>>>(
        sb0, wtt[0], dp_b1, dp_g1, dp_be1, h1s, nullptr, nullptr, nullptr);
    conv_ln_kernel<LL, true><<<BB * LL / 256, 512, 0, stream>>>(
        h1s, wtt[1], dp_b2, dp_g2, dp_be2, nullptr, dp_wl, dp_bl, out + O_DUR);

    // length regulate -> bb0 (bf16 padded)
    gather_kernel<<<BB * MEL * 96 / 256, 256, 0, stream>>>(x, idxm, bb0);

    // pitch predictor (T=4096)
    conv_ln_kernel<MEL, false><<<BB * MEL / 256, 512, 0, stream>>>(
        bb0, wtt[2], pp_b1, pp_g1, pp_be1, h1p, nullptr, nullptr, nullptr);
    conv_ln_kernel<MEL, true><<<BB * MEL / 256, 512, 0, stream>>>(
        h1p, wtt[3], pp_b2, pp_g2, pp_be2, nullptr, pp_wl, pp_bl, out + O_PIT);

    // energy input = bf16(expanded + pitches)
    addp_kernel<<<BB * MEL * 48 / 256, 256, 0, stream>>>(bb0, out + O_PIT, be0);

    // energy predictor (T=4096)
    conv_ln_kernel<MEL, false><<<BB * MEL / 256, 512, 0, stream>>>(
        be0, wtt[4], ep_b1, ep_g1, ep_be1, h1p, nullptr, nullptr, nullptr);
    conv_ln_kernel<MEL, true><<<BB * MEL / 256, 512, 0, stream>>>(
        h1p, wtt[5], ep_b2, ep_g2, ep_be2, nullptr, ep_wl, ep_bl, out + O_EN);

    // final: out = expanded(exact fp32) + pitches + energies
    final_kernel<<<BB * MEL * 96 / 256, 256, 0, stream>>>(
        x, idxm, out + O_PIT, out + O_EN, out + O_OUT);
}

// Round 10
// 431.663 us; speedup vs baseline: 1.4093x; 1.4093x over previous
//
#include <hip/hip_runtime.h>
#include <stdint.h>
#include <stdio.h>

#define BB   16
#define LL   512
#define CC   384
#define FF   384
#define KW   3
#define MEL  4096
#define KKT  (CC*KW)   // 1152

// output section offsets (fp32 elements)
#define O_OUT 0
#define N_OUT (BB*MEL*CC)          // 25165824
#define O_DUR (N_OUT)
#define O_PIT (O_DUR + BB*LL)
#define O_EN  (O_PIT + BB*MEL)

using bf16x8 = __attribute__((ext_vector_type(8))) short;
using f32x4  = __attribute__((ext_vector_type(4))) float;

__device__ __forceinline__ unsigned short f2bf(float v) {
    union { float f; unsigned int u; } cv; cv.f = v;
    unsigned int u = cv.u;
    u += 0x7FFFu + ((u >> 16) & 1u);   // RNE
    return (unsigned short)(u >> 16);
}
__device__ __forceinline__ float bf2f(unsigned short u) {
    union { unsigned int u; float f; } cv; cv.u = ((unsigned int)u) << 16; return cv.f;
}

__device__ __forceinline__ void gld_lds16(const unsigned short* gp, unsigned short* lp) {
    __builtin_amdgcn_global_load_lds(
        (const __attribute__((address_space(1))) unsigned int*)gp,
        (__attribute__((address_space(3))) unsigned int*)lp, 16, 0, 0);
}

// ------ weight transform: w[F][C][K] fp32 -> wt2 step-major chunk-major ----
// wt2[t][c][e]: t in 0..17 (K-step of 64), c = q*384+bn (q=chunk 0..7, bn=col),
// e = 0..7 shorts. Element = w[bn][ch][k] with kk = t*64+q*8+e, ch=kk%384, k=kk/384.
__global__ void wtrans_kernel(const float* __restrict__ w, unsigned short* __restrict__ wt2) {
    int i = blockIdx.x * 256 + threadIdx.x;
    if (i >= FF * KKT) return;
    const int t = i / 24576;
    const int r = i - t * 24576;
    const int c = r >> 3;
    const int e = r & 7;
    const int q = c / 384;
    const int bn = c - q * 384;
    const int kk = t * 64 + q * 8 + e;
    const int k = kk / CC;
    const int ch = kk - k * CC;
    wt2[i] = f2bf(w[(size_t)bn * KKT + ch * KW + k]);
}

// ---------------- x fp32 -> padded bf16 [B][L+2][C] ------------------------
__global__ void convert_x_kernel(const float* __restrict__ x, unsigned short* __restrict__ o) {
    int i = blockIdx.x * 256 + threadIdx.x;
    if (i >= BB * LL * CC) return;
    int b = i / (LL * CC);
    int r = i - b * (LL * CC);
    int t = r / CC;
    int c = r - t * CC;
    o[((size_t)b * (LL + 2) + t + 1) * CC + c] = f2bf(x[i]);
}

// ---------------- zero the two pad rows per batch --------------------------
__global__ void zpad_kernel(unsigned short* __restrict__ buf, int T) {
    int b = blockIdx.x >> 1;
    int w = blockIdx.x & 1;
    size_t row = (size_t)b * (T + 2) + (w ? (T + 1) : 0);
    buf[row * CC + threadIdx.x] = 0;
}

// ---------------- fused Conv(K=3)+bias+ReLU+LN [+Linear] -------------------
// Round-6 proven structure (78.3us/dispatch, 0 bank conflicts), with runtime T
// and DUAL-PROBLEM dispatch: blocks [0,g0) run problem a0, [g0,..) run a1 —
// lets the small T=512 duration convs ride along with the big T=4096 convs.
// Tile M=128 x N=384, BK=64, NT=18. 512 thr, 8 waves (2Mx4N).
// LDS: 2 buffers x 64KB. A: row-major 128B rows, XOR ca=q^(row&7), coalesced
// pre-swizzled source. B: chunk-major cells (0-conflict, coalesced via wt2).
struct CP {
    const unsigned short* inb;
    const unsigned short* wt2;
    const float* bias;
    const float* g;
    const float* be;
    unsigned short* outb;
    const float* wl;
    const float* bl;
    float* op;
    int T;
};

template<bool FL>
__global__ __launch_bounds__(512)
void conv_ln_kernel(CP a0, CP a1, int g0) {
    __shared__ __align__(16) unsigned short LDS[2][32768];

    const CP& a = (blockIdx.x < g0) ? a0 : a1;
    const int blk = (blockIdx.x < g0) ? blockIdx.x : blockIdx.x - g0;
    const int T = a.T;

    constexpr int NT = KKT / 64;   // 18
    const int m0 = blk * 128;
    const int b  = m0 / T;
    const int t0 = m0 - b * T;
    const int tid  = threadIdx.x;
    const int lane = tid & 63;
    const int wv   = tid >> 6;
    const int wr   = wv >> 2;          // 0..1 -> 64 rows
    const int wc   = wv & 3;           // 0..3 -> 96 cols

    // A staging sources (pre-swizzled within 128B row segments -> coalesced)
    const int rowS = tid >> 3;
    const int gch  = (tid & 7) ^ (rowS & 7);
    const unsigned short* srcA0 =
        a.inb + ((size_t)b * (T + 2) + t0 + rowS) * CC + gch * 8;
    const unsigned short* srcA1 =
        a.inb + ((size_t)b * (T + 2) + t0 + 64 + rowS) * CC + gch * 8;
    const unsigned short* srcB = a.wt2 + (size_t)tid * 8;   // + s*4096 + t*24576

    f32x4 acc[4][6] = {};

    auto stage = [&](int bi, int t) {
        const int offA = t * 64;
        gld_lds16(srcA0 + offA, &LDS[bi][(wv * 64) * 8]);
        gld_lds16(srcA1 + offA, &LDS[bi][(512 + wv * 64) * 8]);
        const size_t offB = (size_t)t * 24576;
        #pragma unroll
        for (int s = 0; s < 6; ++s)
            gld_lds16(srcB + offB + s * 4096,
                      &LDS[bi][8192 + (s * 512 + wv * 64) * 8]);
    };

    auto compute = [&](int bi) {
        const int q0 = lane >> 4;
        const int l15 = lane & 15;
        __builtin_amdgcn_s_setprio(1);
        #pragma unroll
        for (int kk = 0; kk < 2; ++kk) {
            bf16x8 af[4], bf[6];
            const int q = 4 * kk + q0;
            const int ca = q ^ (lane & 7);
            #pragma unroll
            for (int i = 0; i < 4; ++i) {
                const int ar = wr * 64 + i * 16 + l15;
                af[i] = *reinterpret_cast<const bf16x8*>(&LDS[bi][(ar * 8 + ca) * 8]);
            }
            #pragma unroll
            for (int j = 0; j < 6; ++j) {
                const int bn = wc * 96 + j * 16 + l15;
                bf[j] = *reinterpret_cast<const bf16x8*>(&LDS[bi][8192 + (q * 384 + bn) * 8]);
            }
            #pragma unroll
            for (int i = 0; i < 4; ++i)
                #pragma unroll
                for (int j = 0; j < 6; ++j)
                    acc[i][j] = __builtin_amdgcn_mfma_f32_16x16x32_bf16(
                        af[i], bf[j], acc[i][j], 0, 0, 0);
        }
        __builtin_amdgcn_s_setprio(0);
    };

    // depth-2 prologue
    stage(0, 0);
    stage(1, 1);

    #pragma unroll 2
    for (int t = 0; t < NT; ++t) {
        asm volatile("s_waitcnt vmcnt(8)" ::: "memory");  // tile t's 8 loads landed
        __builtin_amdgcn_s_barrier();                     // all waves' t-loads in
        asm volatile("" ::: "memory");
        compute(t & 1);
        asm volatile("" ::: "memory");
        __builtin_amdgcn_s_barrier();                     // buf[t&1] fully consumed
        int nt_ = t + 2; if (nt_ > NT - 1) nt_ = NT - 1;  // dup-stage tail
        stage(t & 1, nt_);
    }
    asm volatile("s_waitcnt vmcnt(0)" ::: "memory");      // drain dup stages
    __syncthreads();

    // ---------------- epilogue: bias + ReLU + LN [+ Linear] ----------------
    const int colb = wc * 96 + (lane & 15);
    float b6[6];
    #pragma unroll
    for (int j = 0; j < 6; ++j) b6[j] = a.bias[colb + j * 16];
    #pragma unroll
    for (int i = 0; i < 4; ++i)
        #pragma unroll
        for (int j = 0; j < 6; ++j)
            #pragma unroll
            for (int r = 0; r < 4; ++r) {
                float v = acc[i][j][r] + b6[j];
                acc[i][j][r] = v > 0.f ? v : 0.f;
            }

    // per-row partial sums (16-lane groups share a row)
    float S1[4][4], S2[4][4];
    #pragma unroll
    for (int i = 0; i < 4; ++i)
        #pragma unroll
        for (int r = 0; r < 4; ++r) {
            float s = 0.f, s2 = 0.f;
            #pragma unroll
            for (int j = 0; j < 6; ++j) { const float v = acc[i][j][r]; s += v; s2 += v * v; }
            #pragma unroll
            for (int m = 1; m <= 8; m <<= 1) { s += __shfl_xor(s, m); s2 += __shfl_xor(s2, m); }
            S1[i][r] = s; S2[i][r] = s2;
        }

    float2* red = (float2*)&LDS[0][0];     // 128 rows x 4 col-waves
    if ((lane & 15) == 0) {
        const int q = lane >> 4;
        #pragma unroll
        for (int i = 0; i < 4; ++i)
            #pragma unroll
            for (int r = 0; r < 4; ++r)
                red[(wr * 64 + i * 16 + q * 4 + r) * 4 + wc] = make_float2(S1[i][r], S2[i][r]);
    }
    __syncthreads();

    float g6[6], be6[6];
    #pragma unroll
    for (int j = 0; j < 6; ++j) { g6[j] = a.g[colb + j * 16]; be6[j] = a.be[colb + j * 16]; }

    if (!FL) {
        #pragma unroll
        for (int i = 0; i < 4; ++i)
            #pragma unroll
            for (int r = 0; r < 4; ++r) {
                const int row = wr * 64 + i * 16 + (lane >> 4) * 4 + r;
                const float2 p0 = red[row * 4 + 0], p1 = red[row * 4 + 1];
                const float2 p2 = red[row * 4 + 2], p3 = red[row * 4 + 3];
                const float S = p0.x + p1.x + p2.x + p3.x;
                const float Q = p0.y + p1.y + p2.y + p3.y;
                const float mu = S * (1.f / 384.f);
                const float rs = rsqrtf(Q * (1.f / 384.f) - mu * mu + 1e-5f);
                unsigned short* qp = a.outb + ((size_t)b * (T + 2) + t0 + row + 1) * CC + colb;
                #pragma unroll
                for (int j = 0; j < 6; ++j)
                    qp[j * 16] = f2bf((acc[i][j][r] - mu) * rs * g6[j] + be6[j]);
            }
    } else {
        float wl6[6];
        #pragma unroll
        for (int j = 0; j < 6; ++j) wl6[j] = a.wl[colb + j * 16];
        float* redl = (float*)&LDS[1][0];
        #pragma unroll
        for (int i = 0; i < 4; ++i)
            #pragma unroll
            for (int r = 0; r < 4; ++r) {
                const int row = wr * 64 + i * 16 + (lane >> 4) * 4 + r;
                const float2 p0 = red[row * 4 + 0], p1 = red[row * 4 + 1];
                const float2 p2 = red[row * 4 + 2], p3 = red[row * 4 + 3];
                const float S = p0.x + p1.x + p2.x + p3.x;
                const float Q = p0.y + p1.y + p2.y + p3.y;
                const float mu = S * (1.f / 384.f);
                const float rs = rsqrtf(Q * (1.f / 384.f) - mu * mu + 1e-5f);
                float sl = 0.f;
                #pragma unroll
                for (int j = 0; j < 6; ++j)
                    sl += ((acc[i][j][r] - mu) * rs * g6[j] + be6[j]) * wl6[j];
                #pragma unroll
                for (int m = 1; m <= 8; m <<= 1) sl += __shfl_xor(sl, m);
                if ((lane & 15) == 0) redl[row * 4 + wc] = sl;
            }
        __syncthreads();
        if (tid < 128)
            a.op[m0 + tid] = redl[tid * 4] + redl[tid * 4 + 1] +
                             redl[tid * 4 + 2] + redl[tid * 4 + 3] + a.bl[0];
    }
}

// ---------------- cumsum of dur per batch ----------------------------------
__global__ void cumsum_kernel(const int* __restrict__ dur, int* __restrict__ cum) {
    __shared__ int s[LL];
    const int b = blockIdx.x, t = threadIdx.x;
    s[t] = dur[b * LL + t];
    __syncthreads();
    for (int off = 1; off < LL; off <<= 1) {
        int v = (t >= off) ? s[t - off] : 0;
        __syncthreads();
        s[t] += v;
        __syncthreads();
    }
    cum[b * LL + t] = s[t];
}

// ---------------- frame -> phoneme index (binary search), -1 if masked -----
__global__ void idx_kernel(const int* __restrict__ cum, int* __restrict__ idxm) {
    const int i = blockIdx.x * 256 + threadIdx.x;
    if (i >= BB * MEL) return;
    const int b = i / MEL, t = i - b * MEL;
    const int* cb = cum + b * LL;
    const int total = cb[LL - 1];
    int lo = 0, hi = LL;
    while (lo < hi) {
        const int mid = (lo + hi) >> 1;
        if (cb[mid] <= t) lo = mid + 1; else hi = mid;
    }
    int id = lo > LL - 1 ? LL - 1 : lo;
    idxm[i] = (t < total) ? id : -1;
}

// ---------------- gather: x fp32 -> expanded bf16 padded (bb0) -------------
__global__ void gather_kernel(const float* __restrict__ x, const int* __restrict__ idxm,
                              unsigned short* __restrict__ bb0) {
    const int i = blockIdx.x * 256 + threadIdx.x;   // i < BB*MEL*96
    const int row = i / 96;
    const int c4  = (i - row * 96) * 4;
    const int b = row >> 12, t = row & (MEL - 1);
    const int id = idxm[row];
    float4 v = make_float4(0.f, 0.f, 0.f, 0.f);
    if (id >= 0) v = *(const float4*)(x + ((size_t)b * LL + id) * CC + c4);
    uint2 pk;
    pk.x = (unsigned int)f2bf(v.x) | ((unsigned int)f2bf(v.y) << 16);
    pk.y = (unsigned int)f2bf(v.z) | ((unsigned int)f2bf(v.w) << 16);
    *(uint2*)(bb0 + ((size_t)b * (MEL + 2) + t + 1) * CC + c4) = pk;
}

// ---------------- be0 = bf16(bb0 + pv[row]) (energy conv input) ------------
__global__ void addp_kernel(const unsigned short* __restrict__ bb0,
                            const float* __restrict__ pv,
                            unsigned short* __restrict__ be0) {
    const int i = blockIdx.x * 256 + threadIdx.x;   // i < BB*MEL*48
    const int row = i / 48;
    const int c8  = (i - row * 48) * 8;
    const int b = row >> 12, t = row & (MEL - 1);
    const float p = pv[row];
    const size_t o = ((size_t)b * (MEL + 2) + t + 1) * CC + c8;
    const uint4 in = *(const uint4*)(bb0 + o);
    uint4 ot;
    const unsigned int w[4] = {in.x, in.y, in.z, in.w};
    unsigned int r[4];
    #pragma unroll
    for (int k = 0; k < 4; ++k) {
        const float lo = bf2f((unsigned short)w[k]) + p;
        const float hi = bf2f((unsigned short)(w[k] >> 16)) + p;
        r[k] = (unsigned int)f2bf(lo) | ((unsigned int)f2bf(hi) << 16);
    }
    ot.x = r[0]; ot.y = r[1]; ot.z = r[2]; ot.w = r[3];
    *(uint4*)(be0 + o) = ot;
}

// ---------------- out0 = bf2f(bb0) + pv + ev (bf16 expanded re-read) -------
__global__ void final_kernel(const unsigned short* __restrict__ bb0,
                             const float* __restrict__ pv, const float* __restrict__ ev,
                             float* __restrict__ out0) {
    const int i = blockIdx.x * 256 + threadIdx.x;   // i < BB*MEL*48
    const int row = i / 48;
    const int c8  = (i - row * 48) * 8;
    const int b = row >> 12, t = row & (MEL - 1);
    const float add = pv[row] + ev[row];
    const uint4 in = *(const uint4*)(bb0 + ((size_t)b * (MEL + 2) + t + 1) * CC + c8);
    const unsigned int w[4] = {in.x, in.y, in.z, in.w};
    float4 o0, o1;
    o0.x = bf2f((unsigned short)w[0]) + add; o0.y = bf2f((unsigned short)(w[0] >> 16)) + add;
    o0.z = bf2f((unsigned short)w[1]) + add; o0.w = bf2f((unsigned short)(w[1] >> 16)) + add;
    o1.x = bf2f((unsigned short)w[2]) + add; o1.y = bf2f((unsigned short)(w[2] >> 16)) + add;
    o1.z = bf2f((unsigned short)w[3]) + add; o1.w = bf2f((unsigned short)(w[3] >> 16)) + add;
    float* op = out0 + (size_t)row * CC + c8;
    *(float4*)op = o0;
    *(float4*)(op + 4) = o1;
}

extern "C" void kernel_launch(void* const* d_in, const int* in_sizes, int n_in,
                              void* d_out, int out_size, void* d_ws, size_t ws_size,
                              hipStream_t stream) {
    const float* x = (const float*)d_in[0];
    const float* P[30];
    for (int i = 0; i < 30; ++i) P[i] = (const float*)d_in[1 + i];
    const int* dur = (const int*)d_in[31];
    float* out = (float*)d_out;

    char* ws = (char*)d_ws;
    const size_t WTT_ELEMS = (size_t)FF * KKT;            // 442368
    const size_t WTT_BYTES = WTT_ELEMS * 2;               // 884736
    unsigned short* wtt[6];
    for (int i = 0; i < 6; ++i) wtt[i] = (unsigned short*)(ws + i * WTT_BYTES);
    int* cum  = (int*)(ws + 5308416);
    int* idxm = (int*)(ws + 5341184);
    unsigned short* sb0 = (unsigned short*)(ws + 5603328);                 // [16][514][384]
    unsigned short* h1s = (unsigned short*)(ws + 11919360);                // [16][514][384]
    unsigned short* bb0 = (unsigned short*)(ws + 18235392);                // [16][4098][384]
    unsigned short* h1p = (unsigned short*)(ws + 68616192);                // [16][4098][384]
    unsigned short* be0 = (unsigned short*)(ws + 118996992);               // [16][4098][384]
    const size_t need = 169377792;
    if (ws_size < need)
        fprintf(stderr, "kernel_launch: ws too small: %zu < %zu\n", ws_size, need);

    const float *dp_w1=P[0], *dp_b1=P[1], *dp_g1=P[2], *dp_be1=P[3], *dp_w2=P[4],
                *dp_b2=P[5], *dp_g2=P[6], *dp_be2=P[7], *dp_wl=P[8], *dp_bl=P[9];
    const float *pp_w1=P[10], *pp_b1=P[11], *pp_g1=P[12], *pp_be1=P[13], *pp_w2=P[14],
                *pp_b2=P[15], *pp_g2=P[16], *pp_be2=P[17], *pp_wl=P[18], *pp_bl=P[19];
    const float *ep_w1=P[20], *ep_b1=P[21], *ep_g1=P[22], *ep_be1=P[23], *ep_w2=P[24],
                *ep_b2=P[25], *ep_g2=P[26], *ep_be2=P[27], *ep_wl=P[28], *ep_bl=P[29];

    const int wtg = (int)((WTT_ELEMS + 255) / 256);
    wtrans_kernel<<<wtg, 256, 0, stream>>>(dp_w1, wtt[0]);
    wtrans_kernel<<<wtg, 256, 0, stream>>>(dp_w2, wtt[1]);
    wtrans_kernel<<<wtg, 256, 0, stream>>>(pp_w1, wtt[2]);
    wtrans_kernel<<<wtg, 256, 0, stream>>>(pp_w2, wtt[3]);
    wtrans_kernel<<<wtg, 256, 0, stream>>>(ep_w1, wtt[4]);
    wtrans_kernel<<<wtg, 256, 0, stream>>>(ep_w2, wtt[5]);

    convert_x_kernel<<<(BB * LL * CC + 255) / 256, 256, 0, stream>>>(x, sb0);
    zpad_kernel<<<BB * 2, CC, 0, stream>>>(sb0, LL);
    zpad_kernel<<<BB * 2, CC, 0, stream>>>(h1s, LL);
    zpad_kernel<<<BB * 2, CC, 0, stream>>>(bb0, MEL);
    zpad_kernel<<<BB * 2, CC, 0, stream>>>(h1p, MEL);
    zpad_kernel<<<BB * 2, CC, 0, stream>>>(be0, MEL);

    cumsum_kernel<<<BB, LL, 0, stream>>>(dur, cum);
    idx_kernel<<<(BB * MEL + 255) / 256, 256, 0, stream>>>(cum, idxm);

    // length regulate -> bb0 (bf16 padded)
    gather_kernel<<<BB * MEL * 96 / 256, 256, 0, stream>>>(x, idxm, bb0);

    const int gMEL = BB * MEL / 128;    // 512
    const int gLL  = BB * LL / 128;     // 64

    // combo conv1: pitch conv1 (bb0 -> h1p) + duration conv1 (sb0 -> h1s)
    {
        CP a0 = { bb0, wtt[2], pp_b1, pp_g1, pp_be1, h1p, nullptr, nullptr, nullptr, MEL };
        CP a1 = { sb0, wtt[0], dp_b1, dp_g1, dp_be1, h1s, nullptr, nullptr, nullptr, LL  };
        conv_ln_kernel<false><<<gMEL + gLL, 512, 0, stream>>>(a0, a1, gMEL);
    }
    // combo conv2(FL): pitch conv2 (h1p -> pitches) + duration conv2 (h1s -> durations)
    {
        CP a0 = { h1p, wtt[3], pp_b2, pp_g2, pp_be2, nullptr, pp_wl, pp_bl, out + O_PIT, MEL };
        CP a1 = { h1s, wtt[1], dp_b2, dp_g2, dp_be2, nullptr, dp_wl, dp_bl, out + O_DUR, LL  };
        conv_ln_kernel<true><<<gMEL + gLL, 512, 0, stream>>>(a0, a1, gMEL);
    }

    // energy input = bf16(expanded + pitches)
    addp_kernel<<<BB * MEL * 48 / 256, 256, 0, stream>>>(bb0, out + O_PIT, be0);

    // energy predictor (T=4096)
    {
        CP a0 = { be0, wtt[4], ep_b1, ep_g1, ep_be1, h1p, nullptr, nullptr, nullptr, MEL };
        conv_ln_kernel<false><<<gMEL, 512, 0, stream>>>(a0, a0, gMEL);
    }
    {
        CP a0 = { h1p, wtt[5], ep_b2, ep_g2, ep_be2, nullptr, ep_wl, ep_bl, out + O_EN, MEL };
        conv_ln_kernel<true><<<gMEL, 512, 0, stream>>>(a0, a0, gMEL);
    }

    // final: out = expanded(bf16) + pitches + energies
    final_kernel<<<BB * MEL * 48 / 256, 256, 0, stream>>>(
        bb0, out + O_PIT, out + O_EN, out + O_OUT);
}